// Round 12
// baseline (338.688 us; speedup 1.0000x reference)
//
#include <hip/hip_runtime.h>

// GCN link predictor: z1 = relu(GCNConv(x,W1,b1)); z2 = GCNConv(z1,W2,b2);
// out[e] = dot(z2[src[e]], z2[dst[e]])
// R9: full bf16 data plane (thr 2.07), bf16 MFMA GEMM w/ register-resident W.
// R10: scatter int2 payload + 4 edges/thread; xbf dropped (gemm1 converts x).
// R11: gemm software-pipelined — 128 rows/block (8 strips), 1-strip A-prefetch
//      so loads fly during the MFMA chain; __launch_bounds__(256,2) gives the
//      allocator a 256-VGPR budget (no spill; R8's corruption vector avoided).

typedef __attribute__((ext_vector_type(8))) short short8;  // 8 bf16 = 4 VGPRs
typedef __attribute__((ext_vector_type(4))) float f32x4;

__device__ __forceinline__ unsigned bf16_rne(float x) {
  unsigned u = __builtin_bit_cast(unsigned, x);
  return (u + 0x7FFFu + ((u >> 16) & 1u)) >> 16;
}
__device__ __forceinline__ float bf2f(unsigned short u) {
  return __builtin_bit_cast(float, ((unsigned)u) << 16);
}

// ---------- degree: 4 edges/thread ----------
__global__ __launch_bounds__(256) void deg_kernel(const int* __restrict__ dst,
                                                  int* __restrict__ deg, int E) {
  int base = blockIdx.x * 1024 + threadIdx.x;
#pragma unroll
  for (int i = 0; i < 4; ++i) {
    int e = base + i * 256;
    if (e < E) atomicAdd(&deg[dst[e]], 1);
  }
}

// ---------- block scan (512 elems/block) ----------
__global__ __launch_bounds__(512) void scan1_kernel(const int* __restrict__ in,
                                                    int* __restrict__ tmp,
                                                    int* __restrict__ bsums, int n) {
  __shared__ int sm[2][512];
  int t = threadIdx.x;
  int gid = blockIdx.x * 512 + t;
  int v = (gid < n) ? in[gid] : 0;
  int pp = 0;
  sm[0][t] = v;
  __syncthreads();
  for (int off = 1; off < 512; off <<= 1) {
    int nv = sm[pp][t];
    if (t >= off) nv += sm[pp][t - off];
    sm[pp ^ 1][t] = nv;
    pp ^= 1;
    __syncthreads();
  }
  int inc = sm[pp][t];
  if (gid < n) tmp[gid] = inc;
  if (t == 511) bsums[blockIdx.x] = inc;
}

__global__ __launch_bounds__(256) void scan2_kernel(int* bsums, int nb) {
  __shared__ int sm[2][256];
  int t = threadIdx.x;
  int v = (t < nb) ? bsums[t] : 0;
  int pp = 0;
  sm[0][t] = v;
  __syncthreads();
  for (int off = 1; off < 256; off <<= 1) {
    int nv = sm[pp][t];
    if (t >= off) nv += sm[pp][t - off];
    sm[pp ^ 1][t] = nv;
    pp ^= 1;
    __syncthreads();
  }
  int inc = sm[pp][t];
  if (t < nb) bsums[t] = inc - v;  // exclusive
}

// rowptr from scan, plus dinv = rsqrt(deg+1) fused here
__global__ __launch_bounds__(256) void scan3_kernel(const int* __restrict__ tmp,
                                                    const int* __restrict__ bsums,
                                                    const int* __restrict__ deg,
                                                    int* __restrict__ rowptr,
                                                    float* __restrict__ dinv, int n) {
  int gid = blockIdx.x * 256 + threadIdx.x;
  if (gid < n) {
    rowptr[gid + 1] = tmp[gid] + bsums[gid >> 9];
    dinv[gid] = rsqrtf((float)(deg[gid] + 1));  // +1 self loop
  }
  if (gid == 0) rowptr[0] = 0;
}

// CSR scatter: one int2 {src, eid} store per edge; 4 edges/thread for MLP.
__global__ __launch_bounds__(256) void scatter_kernel(const int* __restrict__ src,
                                                      const int* __restrict__ dst,
                                                      const int* __restrict__ rowptr,
                                                      int* __restrict__ cnt,
                                                      int2* __restrict__ csr, int E) {
  int base = blockIdx.x * 1024 + threadIdx.x;
#pragma unroll
  for (int i = 0; i < 4; ++i) {
    int e = base + i * 256;
    if (e < E) {
      int d = dst[e];
      int pos = rowptr[d] + atomicAdd(&cnt[d], 1);
      csr[pos] = make_int2(src[e], e);
    }
  }
}

// ---------- pack W[128][128] fp32 -> bf16 hi/lo in MFMA B-fragment order ----
// B frag (16x16x32): lane holds B[k=(lane>>4)*8+j][n=lane&15], j=0..7.
// Layout: Wp[half(0=hi,1=lo)][ct(8)][kf(4)][lane(64)][8] bf16.
__global__ __launch_bounds__(256) void wpack_kernel(const float* __restrict__ W,
                                                    short* __restrict__ Wp) {
  int t = blockIdx.x * 256 + threadIdx.x;  // 2048 = ct*256 + kf*64 + lane
  if (t >= 2048) return;
  int lane = t & 63;
  int kf = (t >> 6) & 3;
  int ct = t >> 8;
  int col = ct * 16 + (lane & 15);
  int k0 = kf * 32 + (lane >> 4) * 8;
  short* dh = Wp + ((((0 * 8 + ct) * 4 + kf) * 64) + lane) * 8;
  short* dl = Wp + ((((1 * 8 + ct) * 4 + kf) * 64) + lane) * 8;
  for (int j = 0; j < 8; ++j) {
    float w = W[(k0 + j) * 128 + col];
    unsigned h = bf16_rne(w);
    float hf = __builtin_bit_cast(float, h << 16);
    unsigned lo = bf16_rne(w - hf);
    dh[j] = (short)h;
    dl[j] = (short)lo;
  }
}

// ---------- bf16 MFMA GEMM: out[r,:] = bf16( dinv[r] * (A[r,:] @ W) ) ----
// FP32A=true: A fp32, converted in-register (layer 1). Else A bf16 (layer 2).
// 128 rows/block (8 strips of 16), 4 waves, wave owns 2 col-tiles; W frags
// register-resident; 1-strip A prefetch pipelines loads under the MFMA chain.
template <bool FP32A>
__global__ __launch_bounds__(256, 2) void gemm_kernel(const void* __restrict__ Av,
                                                      const short* __restrict__ Wp,
                                                      const float* __restrict__ dinv,
                                                      unsigned short* __restrict__ out,
                                                      int M) {
  const int wave = threadIdx.x >> 6;
  const int lane = threadIdx.x & 63;
  const int quad = lane >> 4;
  const int l15 = lane & 15;

  // W fragments for this wave's 2 col-tiles (hi+lo, 4 kfrags) -> 64 VGPRs
  short8 Bh[2][4], Bl[2][4];
  const short8* Wp8 = (const short8*)Wp;
#pragma unroll
  for (int c = 0; c < 2; ++c) {
    int ct = wave * 2 + c;
#pragma unroll
    for (int f = 0; f < 4; ++f) {
      Bh[c][f] = Wp8[((0 * 8 + ct) * 4 + f) * 64 + lane];
      Bl[c][f] = Wp8[((1 * 8 + ct) * 4 + f) * 64 + lane];
    }
  }

  const int rb0 = blockIdx.x * 128;
  const int colbase = wave * 32 + l15;

  // prefetch buffers (raw loads; converted at use)
  float4 praw[8];
  short8 pbf[4];
  auto load_strip = [&](int rb) {
    int arow = rb + l15;
    bool rok = arow < M;
    if constexpr (FP32A) {
      const float4* A4 = (const float4*)Av + (size_t)arow * 32;
      const float4 z = make_float4(0.f, 0.f, 0.f, 0.f);
#pragma unroll
      for (int f = 0; f < 4; ++f) {
        praw[2 * f] = rok ? A4[f * 8 + quad * 2] : z;
        praw[2 * f + 1] = rok ? A4[f * 8 + quad * 2 + 1] : z;
      }
    } else {
      const short8 z = {0, 0, 0, 0, 0, 0, 0, 0};
#pragma unroll
      for (int f = 0; f < 4; ++f) {
        pbf[f] = rok ? *(const short8*)((const unsigned short*)Av +
                                        (size_t)arow * 128 + f * 32 + quad * 8)
                     : z;
      }
    }
  };

  load_strip(rb0);

#pragma unroll 1
  for (int s = 0; s < 8; ++s) {
    int rb = rb0 + s * 16;
    if (rb >= M) break;

    // materialize current strip's A fragments from prefetch buffers
    short8 af[4];
    if constexpr (FP32A) {
#pragma unroll
      for (int f = 0; f < 4; ++f) {
        float4 a0 = praw[2 * f], a1 = praw[2 * f + 1];
        float av[8] = {a0.x, a0.y, a0.z, a0.w, a1.x, a1.y, a1.z, a1.w};
#pragma unroll
        for (int j = 0; j < 8; ++j) af[f][j] = (short)bf16_rne(av[j]);
      }
    } else {
#pragma unroll
      for (int f = 0; f < 4; ++f) af[f] = pbf[f];
    }

    // issue next strip's loads — they fly during the MFMA chain below
    if (s < 7) load_strip(rb + 16);

    f32x4 acc0 = {0.f, 0.f, 0.f, 0.f};
    f32x4 acc1 = {0.f, 0.f, 0.f, 0.f};
#pragma unroll
    for (int f = 0; f < 4; ++f) {
      acc0 = __builtin_amdgcn_mfma_f32_16x16x32_bf16(af[f], Bh[0][f], acc0, 0, 0, 0);
      acc1 = __builtin_amdgcn_mfma_f32_16x16x32_bf16(af[f], Bh[1][f], acc1, 0, 0, 0);
      acc0 = __builtin_amdgcn_mfma_f32_16x16x32_bf16(af[f], Bl[0][f], acc0, 0, 0, 0);
      acc1 = __builtin_amdgcn_mfma_f32_16x16x32_bf16(af[f], Bl[1][f], acc1, 0, 0, 0);
    }

    // epilogue: C/D layout col=lane&15, row=quad*4+i
#pragma unroll
    for (int i = 0; i < 4; ++i) {
      int r = rb + quad * 4 + i;
      if (r < M) {
        float d = dinv[r];
        out[(size_t)r * 128 + colbase] = (unsigned short)bf16_rne(acc0[i] * d);
        out[(size_t)r * 128 + colbase + 16] = (unsigned short)bf16_rne(acc1[i] * d);
      }
    }
  }
}

// ---------- aggregation over prescaled bf16 rows ----------
// out[i] = bf16( dinv[i]*(xw[i] + sum_j xw[j]) + b ), fp32 accumulation.
// 16 lanes/node, one ushort8 (16B) per lane per row, neighbor unroll x4.
__global__ __launch_bounds__(256) void agg_kernel(const unsigned short* __restrict__ xw,
                                                  const float* __restrict__ dinv,
                                                  const int* __restrict__ rowptr,
                                                  const int2* __restrict__ csr,
                                                  const float* __restrict__ bias,
                                                  unsigned short* __restrict__ out,
                                                  int relu, int N) {
  int node = blockIdx.x * 16 + (threadIdx.x >> 4);
  int l = threadIdx.x & 15;
  if (node >= N) return;
  const short8* xw8 = (const short8*)xw;  // row = 16 short8 groups
  short8 sv = xw8[(size_t)node * 16 + l];
  float acc[8];
#pragma unroll
  for (int j = 0; j < 8; ++j) acc[j] = bf2f((unsigned short)sv[j]);
  int s = rowptr[node], e = rowptr[node + 1];
  int k = s;
  for (; k + 4 <= e; k += 4) {
    int j0 = csr[k].x, j1 = csr[k + 1].x, j2 = csr[k + 2].x, j3 = csr[k + 3].x;
    short8 v0 = xw8[(size_t)j0 * 16 + l];
    short8 v1 = xw8[(size_t)j1 * 16 + l];
    short8 v2 = xw8[(size_t)j2 * 16 + l];
    short8 v3 = xw8[(size_t)j3 * 16 + l];
#pragma unroll
    for (int j = 0; j < 8; ++j) {
      acc[j] += (bf2f((unsigned short)v0[j]) + bf2f((unsigned short)v1[j])) +
                (bf2f((unsigned short)v2[j]) + bf2f((unsigned short)v3[j]));
    }
  }
  for (; k < e; ++k) {
    short8 v = xw8[(size_t)csr[k].x * 16 + l];
#pragma unroll
    for (int j = 0; j < 8; ++j) acc[j] += bf2f((unsigned short)v[j]);
  }
  float di = dinv[node];
  const float4* b4 = (const float4*)bias;
  float4 bb0 = b4[l * 2], bb1 = b4[l * 2 + 1];
  float bv[8] = {bb0.x, bb0.y, bb0.z, bb0.w, bb1.x, bb1.y, bb1.z, bb1.w};
  short8 o;
#pragma unroll
  for (int j = 0; j < 8; ++j) {
    float v = fmaf(di, acc[j], bv[j]);
    if (relu) v = fmaxf(v, 0.f);
    o[j] = (short)bf16_rne(v);
  }
  ((short8*)out)[(size_t)node * 16 + l] = o;
}

// ---------- decode over dst-CSR, bf16 z2: 16 lanes/node ----------
__global__ __launch_bounds__(256) void decode_kernel(const unsigned short* __restrict__ z,
                                                     const int* __restrict__ rowptr,
                                                     const int2* __restrict__ csr,
                                                     float* __restrict__ out, int N) {
  int node = blockIdx.x * 16 + (threadIdx.x >> 4);
  int l = threadIdx.x & 15;
  if (node >= N) return;
  const short8* z8 = (const short8*)z;
  short8 zv = z8[(size_t)node * 16 + l];
  float zd[8];
#pragma unroll
  for (int j = 0; j < 8; ++j) zd[j] = bf2f((unsigned short)zv[j]);
  int s = rowptr[node], e = rowptr[node + 1];
  int k = s;
  for (; k + 4 <= e; k += 4) {
    int2 c0 = csr[k], c1 = csr[k + 1], c2 = csr[k + 2], c3 = csr[k + 3];
    short8 v0 = z8[(size_t)c0.x * 16 + l];
    short8 v1 = z8[(size_t)c1.x * 16 + l];
    short8 v2 = z8[(size_t)c2.x * 16 + l];
    short8 v3 = z8[(size_t)c3.x * 16 + l];
    float p0 = 0.f, p1 = 0.f, p2 = 0.f, p3 = 0.f;
#pragma unroll
    for (int j = 0; j < 8; ++j) {
      p0 = fmaf(zd[j], bf2f((unsigned short)v0[j]), p0);
      p1 = fmaf(zd[j], bf2f((unsigned short)v1[j]), p1);
      p2 = fmaf(zd[j], bf2f((unsigned short)v2[j]), p2);
      p3 = fmaf(zd[j], bf2f((unsigned short)v3[j]), p3);
    }
#pragma unroll
    for (int off = 8; off > 0; off >>= 1) {
      p0 += __shfl_xor(p0, off);
      p1 += __shfl_xor(p1, off);
      p2 += __shfl_xor(p2, off);
      p3 += __shfl_xor(p3, off);
    }
    if (l == 0) {
      out[c0.y] = p0;
      out[c1.y] = p1;
      out[c2.y] = p2;
      out[c3.y] = p3;
    }
  }
  for (; k < e; ++k) {
    int2 c = csr[k];
    short8 v = z8[(size_t)c.x * 16 + l];
    float p = 0.f;
#pragma unroll
    for (int j = 0; j < 8; ++j) p = fmaf(zd[j], bf2f((unsigned short)v[j]), p);
#pragma unroll
    for (int off = 8; off > 0; off >>= 1) p += __shfl_xor(p, off);
    if (l == 0) out[c.y] = p;
  }
}

extern "C" void kernel_launch(void* const* d_in, const int* in_sizes, int n_in,
                              void* d_out, int out_size, void* d_ws, size_t ws_size,
                              hipStream_t stream) {
  const float* x  = (const float*)d_in[0];
  const int*   ei = (const int*)d_in[1];
  const float* W1 = (const float*)d_in[2];
  const float* b1 = (const float*)d_in[3];
  const float* W2 = (const float*)d_in[4];
  const float* b2 = (const float*)d_in[5];

  const int N = in_sizes[0] / 128;
  const int E = in_sizes[1] / 2;
  const int* src = ei;
  const int* dst = ei + E;

  char* ws = (char*)d_ws;
  size_t off = 0;
  auto alloc = [&](size_t bytes) -> void* {
    void* p = ws + off;
    off += (bytes + 255) & ~(size_t)255;
    return p;
  };
  unsigned short* bufA = (unsigned short*)alloc((size_t)N * 128 * 2);
  unsigned short* bufB = (unsigned short*)alloc((size_t)N * 128 * 2);
  float* dinv    = (float*)alloc((size_t)N * 4);
  int*   rowptr  = (int*)alloc((size_t)(N + 1) * 4);
  int2*  csr     = (int2*)alloc((size_t)E * 8);
  short* Wp1     = (short*)alloc((size_t)2 * 8 * 4 * 64 * 8 * 2);
  short* Wp2     = (short*)alloc((size_t)2 * 8 * 4 * 64 * 8 * 2);
  int*   tmp     = (int*)alloc((size_t)N * 4);
  int*   deg     = (int*)alloc((size_t)N * 4);   // zeroed region starts here
  int*   cnt     = (int*)alloc((size_t)N * 4);
  int*   bsums   = (int*)alloc(1024);
  size_t zbytes = ((char*)bsums + 1024) - (char*)deg;
  hipMemsetAsync(deg, 0, zbytes, stream);

  const int E4B = (E + 1023) / 1024;
  const int NB = (N + 255) / 256;
  const int SB = (N + 511) / 512;

  // W packing (independent of graph prep)
  wpack_kernel<<<8, 256, 0, stream>>>(W1, Wp1);
  wpack_kernel<<<8, 256, 0, stream>>>(W2, Wp2);

  deg_kernel<<<E4B, 256, 0, stream>>>(dst, deg, E);
  scan1_kernel<<<SB, 512, 0, stream>>>(deg, tmp, bsums, N);
  scan2_kernel<<<1, 256, 0, stream>>>(bsums, SB);
  scan3_kernel<<<NB, 256, 0, stream>>>(tmp, bsums, deg, rowptr, dinv, N);
  scatter_kernel<<<E4B, 256, 0, stream>>>(src, dst, rowptr, cnt, csr, E);

  const int GB = (N + 127) / 128;
  const int AB = (N + 15) / 16;
  const int DB = (N + 15) / 16;

  // layer 1 (A = x, fp32 -> bf16 in-register)
  gemm_kernel<true><<<GB, 256, 0, stream>>>(x, Wp1, dinv, bufA, N);
  agg_kernel<<<AB, 256, 0, stream>>>(bufA, dinv, rowptr, csr, b1, bufB, 1, N);
  // layer 2 (A = z1, bf16)
  gemm_kernel<false><<<GB, 256, 0, stream>>>(bufB, Wp2, dinv, bufA, N);
  agg_kernel<<<AB, 256, 0, stream>>>(bufA, dinv, rowptr, csr, b2, bufB, 0, N);
  // decode over dst-CSR
  decode_kernel<<<DB, 256, 0, stream>>>(bufB, rowptr, csr, (float*)d_out, N);
}

// Round 13
// 330.877 us; speedup vs baseline: 1.0236x; 1.0236x over previous
//
#include <hip/hip_runtime.h>

// GCN link predictor: z1 = relu(GCNConv(x,W1,b1)); z2 = GCNConv(z1,W2,b2);
// out[e] = dot(z2[src[e]], z2[dst[e]])
// R9/R10: bf16 data plane (thr 2.07), int2 CSR scatter, MFMA gemm.
// R13: gemm flattened for memory-level parallelism — ALL loads (16 W frags +
//      16 A frags spanning the block's 4 strips) issue before any MFMA; one
//      latency exposure per wave, 8 independent MFMA chains. xbf reinstated
//      so both layers use the 16B bf16 A path. Rolling prefetch (R8/R11)
//      abandoned: 130-cyc MFMA chain can't hide 900-cyc loads.

typedef __attribute__((ext_vector_type(8))) short short8;  // 8 bf16 = 4 VGPRs
typedef __attribute__((ext_vector_type(4))) float f32x4;

__device__ __forceinline__ unsigned bf16_rne(float x) {
  unsigned u = __builtin_bit_cast(unsigned, x);
  return (u + 0x7FFFu + ((u >> 16) & 1u)) >> 16;
}
__device__ __forceinline__ float bf2f(unsigned short u) {
  return __builtin_bit_cast(float, ((unsigned)u) << 16);
}

// ---------- degree: 4 edges/thread ----------
__global__ __launch_bounds__(256) void deg_kernel(const int* __restrict__ dst,
                                                  int* __restrict__ deg, int E) {
  int base = blockIdx.x * 1024 + threadIdx.x;
#pragma unroll
  for (int i = 0; i < 4; ++i) {
    int e = base + i * 256;
    if (e < E) atomicAdd(&deg[dst[e]], 1);
  }
}

// ---------- block scan (512 elems/block) ----------
__global__ __launch_bounds__(512) void scan1_kernel(const int* __restrict__ in,
                                                    int* __restrict__ tmp,
                                                    int* __restrict__ bsums, int n) {
  __shared__ int sm[2][512];
  int t = threadIdx.x;
  int gid = blockIdx.x * 512 + t;
  int v = (gid < n) ? in[gid] : 0;
  int pp = 0;
  sm[0][t] = v;
  __syncthreads();
  for (int off = 1; off < 512; off <<= 1) {
    int nv = sm[pp][t];
    if (t >= off) nv += sm[pp][t - off];
    sm[pp ^ 1][t] = nv;
    pp ^= 1;
    __syncthreads();
  }
  int inc = sm[pp][t];
  if (gid < n) tmp[gid] = inc;
  if (t == 511) bsums[blockIdx.x] = inc;
}

__global__ __launch_bounds__(256) void scan2_kernel(int* bsums, int nb) {
  __shared__ int sm[2][256];
  int t = threadIdx.x;
  int v = (t < nb) ? bsums[t] : 0;
  int pp = 0;
  sm[0][t] = v;
  __syncthreads();
  for (int off = 1; off < 256; off <<= 1) {
    int nv = sm[pp][t];
    if (t >= off) nv += sm[pp][t - off];
    sm[pp ^ 1][t] = nv;
    pp ^= 1;
    __syncthreads();
  }
  int inc = sm[pp][t];
  if (t < nb) bsums[t] = inc - v;  // exclusive
}

// rowptr from scan, plus dinv = rsqrt(deg+1) fused here
__global__ __launch_bounds__(256) void scan3_kernel(const int* __restrict__ tmp,
                                                    const int* __restrict__ bsums,
                                                    const int* __restrict__ deg,
                                                    int* __restrict__ rowptr,
                                                    float* __restrict__ dinv, int n) {
  int gid = blockIdx.x * 256 + threadIdx.x;
  if (gid < n) {
    rowptr[gid + 1] = tmp[gid] + bsums[gid >> 9];
    dinv[gid] = rsqrtf((float)(deg[gid] + 1));  // +1 self loop
  }
  if (gid == 0) rowptr[0] = 0;
}

// CSR scatter: one int2 {src, eid} store per edge; 4 edges/thread for MLP.
__global__ __launch_bounds__(256) void scatter_kernel(const int* __restrict__ src,
                                                      const int* __restrict__ dst,
                                                      const int* __restrict__ rowptr,
                                                      int* __restrict__ cnt,
                                                      int2* __restrict__ csr, int E) {
  int base = blockIdx.x * 1024 + threadIdx.x;
#pragma unroll
  for (int i = 0; i < 4; ++i) {
    int e = base + i * 256;
    if (e < E) {
      int d = dst[e];
      int pos = rowptr[d] + atomicAdd(&cnt[d], 1);
      csr[pos] = make_int2(src[e], e);
    }
  }
}

// ---------- x fp32 -> bf16 (row-major, one-shot) ----------
__global__ __launch_bounds__(256) void xbf_kernel(const float* __restrict__ x,
                                                  unsigned short* __restrict__ xb,
                                                  int total8) {
  int i = blockIdx.x * 256 + threadIdx.x;
  if (i >= total8) return;
  const float4* p = (const float4*)x + (size_t)i * 2;
  float4 a = p[0], b = p[1];
  float av[8] = {a.x, a.y, a.z, a.w, b.x, b.y, b.z, b.w};
  short8 o;
#pragma unroll
  for (int j = 0; j < 8; ++j) o[j] = (short)bf16_rne(av[j]);
  ((short8*)xb)[i] = o;
}

// ---------- pack W[128][128] fp32 -> bf16 hi/lo in MFMA B-fragment order ----
// B frag (16x16x32): lane holds B[k=(lane>>4)*8+j][n=lane&15], j=0..7.
// Layout: Wp[half(0=hi,1=lo)][ct(8)][kf(4)][lane(64)][8] bf16.
__global__ __launch_bounds__(256) void wpack_kernel(const float* __restrict__ W,
                                                    short* __restrict__ Wp) {
  int t = blockIdx.x * 256 + threadIdx.x;  // 2048 = ct*256 + kf*64 + lane
  if (t >= 2048) return;
  int lane = t & 63;
  int kf = (t >> 6) & 3;
  int ct = t >> 8;
  int col = ct * 16 + (lane & 15);
  int k0 = kf * 32 + (lane >> 4) * 8;
  short* dh = Wp + ((((0 * 8 + ct) * 4 + kf) * 64) + lane) * 8;
  short* dl = Wp + ((((1 * 8 + ct) * 4 + kf) * 64) + lane) * 8;
  for (int j = 0; j < 8; ++j) {
    float w = W[(k0 + j) * 128 + col];
    unsigned h = bf16_rne(w);
    float hf = __builtin_bit_cast(float, h << 16);
    unsigned lo = bf16_rne(w - hf);
    dh[j] = (short)h;
    dl[j] = (short)lo;
  }
}

// ---------- bf16 MFMA GEMM: out[r,:] = bf16( dinv[r] * (A[r,:] @ W) ) ----
// 64 rows/block, 4 waves, wave owns 2 col-tiles. FLAT structure: all 16 W-frag
// loads + all 16 A-frag loads (4 strips) issue before any MFMA — one latency
// exposure per wave, then 64 MFMAs over 8 independent chains (depth 8).
__global__ __launch_bounds__(256) void gemm_kernel(const unsigned short* __restrict__ A,
                                                   const short* __restrict__ Wp,
                                                   const float* __restrict__ dinv,
                                                   unsigned short* __restrict__ out,
                                                   int M) {
  const int wave = threadIdx.x >> 6;
  const int lane = threadIdx.x & 63;
  const int quad = lane >> 4;
  const int l15 = lane & 15;

  // W fragments for this wave's 2 col-tiles (hi+lo, 4 kfrags) -> 64 VGPRs
  short8 Bh[2][4], Bl[2][4];
  const short8* Wp8 = (const short8*)Wp;
#pragma unroll
  for (int c = 0; c < 2; ++c) {
    int ct = wave * 2 + c;
#pragma unroll
    for (int f = 0; f < 4; ++f) {
      Bh[c][f] = Wp8[((0 * 8 + ct) * 4 + f) * 64 + lane];
      Bl[c][f] = Wp8[((1 * 8 + ct) * 4 + f) * 64 + lane];
    }
  }

  const int rb0 = blockIdx.x * 64;

  // A fragments for all 4 strips -> 64 VGPRs, all loads in flight together
  short8 af[4][4];
  const short8 zf = {0, 0, 0, 0, 0, 0, 0, 0};
#pragma unroll
  for (int s = 0; s < 4; ++s) {
    int arow = rb0 + s * 16 + l15;
    bool rok = arow < M;
#pragma unroll
    for (int f = 0; f < 4; ++f) {
      af[s][f] = rok ? *(const short8*)(A + (size_t)arow * 128 + f * 32 + quad * 8)
                     : zf;
    }
  }

  // 8 independent MFMA chains: [strip][coltile], depth 8 each
  f32x4 acc[4][2];
#pragma unroll
  for (int s = 0; s < 4; ++s) {
    acc[s][0] = (f32x4){0.f, 0.f, 0.f, 0.f};
    acc[s][1] = (f32x4){0.f, 0.f, 0.f, 0.f};
  }
#pragma unroll
  for (int f = 0; f < 4; ++f) {
#pragma unroll
    for (int s = 0; s < 4; ++s) {
      acc[s][0] = __builtin_amdgcn_mfma_f32_16x16x32_bf16(af[s][f], Bh[0][f], acc[s][0], 0, 0, 0);
      acc[s][1] = __builtin_amdgcn_mfma_f32_16x16x32_bf16(af[s][f], Bh[1][f], acc[s][1], 0, 0, 0);
      acc[s][0] = __builtin_amdgcn_mfma_f32_16x16x32_bf16(af[s][f], Bl[0][f], acc[s][0], 0, 0, 0);
      acc[s][1] = __builtin_amdgcn_mfma_f32_16x16x32_bf16(af[s][f], Bl[1][f], acc[s][1], 0, 0, 0);
    }
  }

  // epilogue: C/D layout col=lane&15, row=quad*4+i
  const int colbase = wave * 32 + l15;
#pragma unroll
  for (int s = 0; s < 4; ++s) {
#pragma unroll
    for (int i = 0; i < 4; ++i) {
      int r = rb0 + s * 16 + quad * 4 + i;
      if (r < M) {
        float d = dinv[r];
        out[(size_t)r * 128 + colbase] = (unsigned short)bf16_rne(acc[s][0][i] * d);
        out[(size_t)r * 128 + colbase + 16] = (unsigned short)bf16_rne(acc[s][1][i] * d);
      }
    }
  }
}

// ---------- aggregation over prescaled bf16 rows ----------
// out[i] = bf16( dinv[i]*(xw[i] + sum_j xw[j]) + b ), fp32 accumulation.
// 16 lanes/node, one ushort8 (16B) per lane per row, neighbor unroll x4.
__global__ __launch_bounds__(256) void agg_kernel(const unsigned short* __restrict__ xw,
                                                  const float* __restrict__ dinv,
                                                  const int* __restrict__ rowptr,
                                                  const int2* __restrict__ csr,
                                                  const float* __restrict__ bias,
                                                  unsigned short* __restrict__ out,
                                                  int relu, int N) {
  int node = blockIdx.x * 16 + (threadIdx.x >> 4);
  int l = threadIdx.x & 15;
  if (node >= N) return;
  const short8* xw8 = (const short8*)xw;  // row = 16 short8 groups
  short8 sv = xw8[(size_t)node * 16 + l];
  float acc[8];
#pragma unroll
  for (int j = 0; j < 8; ++j) acc[j] = bf2f((unsigned short)sv[j]);
  int s = rowptr[node], e = rowptr[node + 1];
  int k = s;
  for (; k + 4 <= e; k += 4) {
    int j0 = csr[k].x, j1 = csr[k + 1].x, j2 = csr[k + 2].x, j3 = csr[k + 3].x;
    short8 v0 = xw8[(size_t)j0 * 16 + l];
    short8 v1 = xw8[(size_t)j1 * 16 + l];
    short8 v2 = xw8[(size_t)j2 * 16 + l];
    short8 v3 = xw8[(size_t)j3 * 16 + l];
#pragma unroll
    for (int j = 0; j < 8; ++j) {
      acc[j] += (bf2f((unsigned short)v0[j]) + bf2f((unsigned short)v1[j])) +
                (bf2f((unsigned short)v2[j]) + bf2f((unsigned short)v3[j]));
    }
  }
  for (; k < e; ++k) {
    short8 v = xw8[(size_t)csr[k].x * 16 + l];
#pragma unroll
    for (int j = 0; j < 8; ++j) acc[j] += bf2f((unsigned short)v[j]);
  }
  float di = dinv[node];
  const float4* b4 = (const float4*)bias;
  float4 bb0 = b4[l * 2], bb1 = b4[l * 2 + 1];
  float bv[8] = {bb0.x, bb0.y, bb0.z, bb0.w, bb1.x, bb1.y, bb1.z, bb1.w};
  short8 o;
#pragma unroll
  for (int j = 0; j < 8; ++j) {
    float v = fmaf(di, acc[j], bv[j]);
    if (relu) v = fmaxf(v, 0.f);
    o[j] = (short)bf16_rne(v);
  }
  ((short8*)out)[(size_t)node * 16 + l] = o;
}

// ---------- decode over dst-CSR, bf16 z2: 16 lanes/node ----------
__global__ __launch_bounds__(256) void decode_kernel(const unsigned short* __restrict__ z,
                                                     const int* __restrict__ rowptr,
                                                     const int2* __restrict__ csr,
                                                     float* __restrict__ out, int N) {
  int node = blockIdx.x * 16 + (threadIdx.x >> 4);
  int l = threadIdx.x & 15;
  if (node >= N) return;
  const short8* z8 = (const short8*)z;
  short8 zv = z8[(size_t)node * 16 + l];
  float zd[8];
#pragma unroll
  for (int j = 0; j < 8; ++j) zd[j] = bf2f((unsigned short)zv[j]);
  int s = rowptr[node], e = rowptr[node + 1];
  int k = s;
  for (; k + 4 <= e; k += 4) {
    int2 c0 = csr[k], c1 = csr[k + 1], c2 = csr[k + 2], c3 = csr[k + 3];
    short8 v0 = z8[(size_t)c0.x * 16 + l];
    short8 v1 = z8[(size_t)c1.x * 16 + l];
    short8 v2 = z8[(size_t)c2.x * 16 + l];
    short8 v3 = z8[(size_t)c3.x * 16 + l];
    float p0 = 0.f, p1 = 0.f, p2 = 0.f, p3 = 0.f;
#pragma unroll
    for (int j = 0; j < 8; ++j) {
      p0 = fmaf(zd[j], bf2f((unsigned short)v0[j]), p0);
      p1 = fmaf(zd[j], bf2f((unsigned short)v1[j]), p1);
      p2 = fmaf(zd[j], bf2f((unsigned short)v2[j]), p2);
      p3 = fmaf(zd[j], bf2f((unsigned short)v3[j]), p3);
    }
#pragma unroll
    for (int off = 8; off > 0; off >>= 1) {
      p0 += __shfl_xor(p0, off);
      p1 += __shfl_xor(p1, off);
      p2 += __shfl_xor(p2, off);
      p3 += __shfl_xor(p3, off);
    }
    if (l == 0) {
      out[c0.y] = p0;
      out[c1.y] = p1;
      out[c2.y] = p2;
      out[c3.y] = p3;
    }
  }
  for (; k < e; ++k) {
    int2 c = csr[k];
    short8 v = z8[(size_t)c.x * 16 + l];
    float p = 0.f;
#pragma unroll
    for (int j = 0; j < 8; ++j) p = fmaf(zd[j], bf2f((unsigned short)v[j]), p);
#pragma unroll
    for (int off = 8; off > 0; off >>= 1) p += __shfl_xor(p, off);
    if (l == 0) out[c.y] = p;
  }
}

extern "C" void kernel_launch(void* const* d_in, const int* in_sizes, int n_in,
                              void* d_out, int out_size, void* d_ws, size_t ws_size,
                              hipStream_t stream) {
  const float* x  = (const float*)d_in[0];
  const int*   ei = (const int*)d_in[1];
  const float* W1 = (const float*)d_in[2];
  const float* b1 = (const float*)d_in[3];
  const float* W2 = (const float*)d_in[4];
  const float* b2 = (const float*)d_in[5];

  const int N = in_sizes[0] / 128;
  const int E = in_sizes[1] / 2;
  const int* src = ei;
  const int* dst = ei + E;

  char* ws = (char*)d_ws;
  size_t off = 0;
  auto alloc = [&](size_t bytes) -> void* {
    void* p = ws + off;
    off += (bytes + 255) & ~(size_t)255;
    return p;
  };
  unsigned short* xb   = (unsigned short*)alloc((size_t)N * 128 * 2);
  unsigned short* bufA = (unsigned short*)alloc((size_t)N * 128 * 2);
  unsigned short* bufB = (unsigned short*)alloc((size_t)N * 128 * 2);
  float* dinv    = (float*)alloc((size_t)N * 4);
  int*   rowptr  = (int*)alloc((size_t)(N + 1) * 4);
  int2*  csr     = (int2*)alloc((size_t)E * 8);
  short* Wp1     = (short*)alloc((size_t)2 * 8 * 4 * 64 * 8 * 2);
  short* Wp2     = (short*)alloc((size_t)2 * 8 * 4 * 64 * 8 * 2);
  int*   tmp     = (int*)alloc((size_t)N * 4);
  int*   deg     = (int*)alloc((size_t)N * 4);   // zeroed region starts here
  int*   cnt     = (int*)alloc((size_t)N * 4);
  int*   bsums   = (int*)alloc(1024);
  size_t zbytes = ((char*)bsums + 1024) - (char*)deg;
  hipMemsetAsync(deg, 0, zbytes, stream);

  const int E4B = (E + 1023) / 1024;
  const int NB = (N + 255) / 256;
  const int SB = (N + 511) / 512;
  const int total8 = N * 16;  // N*128/8

  // conversions / packing (independent of graph prep)
  xbf_kernel<<<(total8 + 255) / 256, 256, 0, stream>>>(x, xb, total8);
  wpack_kernel<<<8, 256, 0, stream>>>(W1, Wp1);
  wpack_kernel<<<8, 256, 0, stream>>>(W2, Wp2);

  deg_kernel<<<E4B, 256, 0, stream>>>(dst, deg, E);
  scan1_kernel<<<SB, 512, 0, stream>>>(deg, tmp, bsums, N);
  scan2_kernel<<<1, 256, 0, stream>>>(bsums, SB);
  scan3_kernel<<<NB, 256, 0, stream>>>(tmp, bsums, deg, rowptr, dinv, N);
  scatter_kernel<<<E4B, 256, 0, stream>>>(src, dst, rowptr, cnt, csr, E);

  const int GB = (N + 63) / 64;
  const int AB = (N + 15) / 16;
  const int DB = (N + 15) / 16;

  // layer 1 (A = bf16 x)
  gemm_kernel<<<GB, 256, 0, stream>>>(xb, Wp1, dinv, bufA, N);
  agg_kernel<<<AB, 256, 0, stream>>>(bufA, dinv, rowptr, csr, b1, bufB, 1, N);
  // layer 2 (A = bf16 z1)
  gemm_kernel<<<GB, 256, 0, stream>>>(bufB, Wp2, dinv, bufA, N);
  agg_kernel<<<AB, 256, 0, stream>>>(bufA, dinv, rowptr, csr, b2, bufB, 0, N);
  // decode over dst-CSR
  decode_kernel<<<DB, 256, 0, stream>>>(bufB, rowptr, csr, (float*)d_out, N);
}